// Round 5
// baseline (108.158 us; speedup 1.0000x reference)
//
#include <hip/hip_runtime.h>
#include <math.h>

#define HALF_PI   1.57079632679489662f
#define INV_SQRT2 0.70710678118654752f
#define GB    512                 // grid blocks (<= half of guaranteed capacity)
#define BT    256                 // threads per block
#define NTH   (GB * BT)           // 131072 threads
#define MAXIT 2                   // edge groups per thread: E <= NTH*4*MAXIT = 1048576

// Device-scope grid barrier (same lowering HIP cooperative grid.sync uses).
// Safe because __launch_bounds__(BT,2) caps VGPR at 256 -> >=2 blocks/CU
// resident -> capacity 1024 >= GB=512 (2x margin), so all blocks are
// co-resident and the spin always terminates.
__device__ __forceinline__ void gridbar(int* cnt, int* flag) {
    __syncthreads();
    if (threadIdx.x == 0) {
        int v = __hip_atomic_fetch_add(cnt, 1, __ATOMIC_ACQ_REL, __HIP_MEMORY_SCOPE_AGENT);
        if (v == GB - 1) {
            __hip_atomic_store(flag, 1, __ATOMIC_RELEASE, __HIP_MEMORY_SCOPE_AGENT);
        } else {
            while (__hip_atomic_load(flag, __ATOMIC_ACQUIRE, __HIP_MEMORY_SCOPE_AGENT) == 0) {
                __builtin_amdgcn_s_sleep(2);
            }
        }
    }
    __syncthreads();
}

// 4-qubit real circuit for one edge: returns exp(attn/4)
__device__ __forceinline__ float edge_ex(float4 qv, float4 kv,
                                         const float* scz, const float* scx) {
    float qa[4] = {qv.x, qv.y, qv.z, qv.w};
    float ka[4] = {kv.x, kv.y, kv.z, kv.w};
    float u[4][2];
    #pragma unroll
    for (int w = 0; w < 4; ++w) {
        float s, c;
        __sincosf(qa[w] * 0.5f, &s, &c);
        u[w][0] = (c + s) * INV_SQRT2;
        u[w][1] = (c - s) * INV_SQRT2;
    }
    float a[16];
    #pragma unroll
    for (int x = 0; x < 16; ++x)
        a[x] = u[0][(x >> 3) & 1] * u[1][(x >> 2) & 1] *
               u[2][(x >> 1) & 1] * u[3][x & 1];
    #pragma unroll
    for (int w = 0; w < 4; ++w) {
        float si, co;
        __sincosf(ka[w] * 0.5f, &si, &co);
        const int cb = 1 << (3 - w);
        const int tb = 1 << (3 - ((w + 1) & 3));
        #pragma unroll
        for (int x = 0; x < 16; ++x) {
            if ((x & cb) && !(x & tb)) {
                float a0 = a[x], a1 = a[x | tb];
                a[x]      = co * a0 - si * a1;
                a[x | tb] = si * a0 + co * a1;
            }
        }
    }
    float attn = 0.f;
    #pragma unroll
    for (int q = 0; q < 4; ++q) {
        const int bit = 1 << (3 - q);
        float sz = 0.f, sx = 0.f;
        #pragma unroll
        for (int x = 0; x < 16; ++x) {
            float pp = a[x] * a[x];
            sz += (x & bit) ? -pp : pp;
            if (!(x & bit)) sx += a[x] * a[x | bit];
        }
        attn += scz[q] * sz - scx[q] * (2.f * sx);
    }
    return __expf(attn * 0.25f);
}

__global__ __launch_bounds__(BT, 2) void fused_qattn(
        const float* __restrict__ feat, const int* __restrict__ ei,
        const float* __restrict__ Wq, const float* __restrict__ bq,
        const float* __restrict__ Wk, const float* __restrict__ bk,
        const float* __restrict__ qp,
        int* bar, float* partial, float* qtab, float* ktab,
        float* __restrict__ out, int N, int E)
{
    __shared__ float scz[4], scx[4];
    __shared__ float red[BT];
    const int tid = threadIdx.x;

    if (tid < 4) {
        float phi = qp[3 * tid + 0];
        float th  = qp[3 * tid + 1];
        float sth, cth;
        sincosf(th, &sth, &cth);
        scz[tid] = cth;
        scx[tid] = sth * cosf(phi);
    }

    // ---------------- Phase A: node projections ----------------
    {
        const int lane = tid & 63;
        const int wid  = (blockIdx.x * BT + tid) >> 6;   // 0..2047
        const int nwid = NTH >> 6;                        // 2048 waves

        float4 wq4[4], wk4[4];
        #pragma unroll
        for (int q = 0; q < 4; ++q) {
            wq4[q] = reinterpret_cast<const float4*>(Wq + q * 256)[lane];
            wk4[q] = reinterpret_cast<const float4*>(Wk + q * 256)[lane];
        }
        const int   g    = lane >> 3;
        const float bias = (g < 4) ? bq[g] : bk[g & 3];
        const bool hi  = (lane & 32) != 0;
        const bool s16 = (lane & 16) != 0;
        const bool s8  = (lane & 8)  != 0;

        for (int nb = wid * 2; nb < N; nb += nwid * 2) {
            float4 f[2];
            float  acc[2][8];
            #pragma unroll
            for (int p = 0; p < 2; ++p) {
                const int n = nb + p;
                if (n < N) f[p] = reinterpret_cast<const float4*>(feat)[(size_t)n * 64 + lane];
                else       f[p] = make_float4(0.f, 0.f, 0.f, 0.f);
                #pragma unroll
                for (int q = 0; q < 4; ++q) {
                    acc[p][q]     = f[p].x * wq4[q].x + f[p].y * wq4[q].y + f[p].z * wq4[q].z + f[p].w * wq4[q].w;
                    acc[p][4 + q] = f[p].x * wk4[q].x + f[p].y * wk4[q].y + f[p].z * wk4[q].z + f[p].w * wk4[q].w;
                }
            }
            #pragma unroll
            for (int p = 0; p < 2; ++p) {
                const int n = nb + p;
                // multi-value butterfly: 10 shuffles per node
                #pragma unroll
                for (int j = 0; j < 4; ++j) {
                    float give = hi ? acc[p][j] : acc[p][j + 4];
                    float r = __shfl_xor(give, 32, 64);
                    acc[p][j]     += hi ? 0.f : r;
                    acc[p][j + 4] += hi ? r : 0.f;
                }
                #pragma unroll
                for (int j = 0; j < 2; ++j) {
                    float giveLow  = hi ? acc[p][6 + j] : acc[p][2 + j];
                    float giveHigh = hi ? acc[p][4 + j] : acc[p][j];
                    float give = s16 ? giveHigh : giveLow;
                    float r = __shfl_xor(give, 16, 64);
                    acc[p][j]     += (!hi && !s16) ? r : 0.f;
                    acc[p][2 + j] += (!hi &&  s16) ? r : 0.f;
                    acc[p][4 + j] += ( hi && !s16) ? r : 0.f;
                    acc[p][6 + j] += ( hi &&  s16) ? r : 0.f;
                }
                float a_even = hi ? (s16 ? acc[p][6] : acc[p][4]) : (s16 ? acc[p][2] : acc[p][0]);
                float a_odd  = hi ? (s16 ? acc[p][7] : acc[p][5]) : (s16 ? acc[p][3] : acc[p][1]);
                float give3 = s8 ? a_even : a_odd;
                float r3 = __shfl_xor(give3, 8, 64);
                float v = (s8 ? a_odd : a_even) + r3;
                v += __shfl_xor(v, 4, 64);
                v += __shfl_xor(v, 2, 64);
                v += __shfl_xor(v, 1, 64);

                if (n < N && (lane & 7) == 0) {
                    float t = tanhf(v + bias) * HALF_PI;
                    if (g < 4) qtab[(size_t)n * 4 + g] = t;
                    else       ktab[(size_t)n * 4 + (g & 3)] = t;
                }
            }
        }
    }

    gridbar(bar + 0, bar + 32);

    // ---------------- Phase B: per-edge circuit ----------------
    const float4* qtab4 = reinterpret_cast<const float4*>(qtab);
    const float4* ktab4 = reinterpret_cast<const float4*>(ktab);
    const int t4 = (blockIdx.x * BT + tid) * 4;
    const bool dal = ((E & 3) == 0);

    float ex[MAXIT][4];
    float lsum = 0.f;
    #pragma unroll
    for (int it = 0; it < MAXIT; ++it) {
        const int base = t4 + it * (NTH * 4);
        #pragma unroll
        for (int j = 0; j < 4; ++j) ex[it][j] = 0.f;
        if (base < E) {
            int s[4], d[4];
            if (dal && base + 3 < E) {
                int4 sv = *reinterpret_cast<const int4*>(ei + base);
                int4 dv = *reinterpret_cast<const int4*>(ei + E + base);
                s[0] = sv.x; s[1] = sv.y; s[2] = sv.z; s[3] = sv.w;
                d[0] = dv.x; d[1] = dv.y; d[2] = dv.z; d[3] = dv.w;
            } else {
                #pragma unroll
                for (int j = 0; j < 4; ++j) {
                    const int e = base + j;
                    s[j] = (e < E) ? ei[e] : 0;
                    d[j] = (e < E) ? ei[E + e] : 0;
                }
            }
            #pragma unroll
            for (int j = 0; j < 4; ++j) {
                const int e = base + j;
                if (e < E) {
                    float v = edge_ex(qtab4[s[j]], ktab4[d[j]], scz, scx);
                    ex[it][j] = v;
                    lsum += v;
                }
            }
        }
    }

    red[tid] = lsum;
    __syncthreads();
    #pragma unroll
    for (int s = 128; s > 0; s >>= 1) {
        if (tid < s) red[tid] += red[tid + s];
        __syncthreads();
    }
    if (tid == 0) partial[blockIdx.x] = red[0];

    gridbar(bar + 64, bar + 96);

    // ---------------- Phase C: redundant reduce + normalize ----------------
    float ps = partial[tid] + partial[tid + BT];   // GB = 2*BT partials
    red[tid] = ps;
    __syncthreads();
    #pragma unroll
    for (int s = 128; s > 0; s >>= 1) {
        if (tid < s) red[tid] += red[tid + s];
        __syncthreads();
    }
    const float inv = 1.f / red[0];

    #pragma unroll
    for (int it = 0; it < MAXIT; ++it) {
        const int base = t4 + it * (NTH * 4);
        if (base + 3 < E) {
            float4 o = make_float4(ex[it][0] * inv, ex[it][1] * inv,
                                   ex[it][2] * inv, ex[it][3] * inv);
            *reinterpret_cast<float4*>(out + base) = o;
        } else {
            #pragma unroll
            for (int j = 0; j < 4; ++j) {
                const int e = base + j;
                if (e < E) out[e] = ex[it][j] * inv;
            }
        }
    }
}

extern "C" void kernel_launch(void* const* d_in, const int* in_sizes, int n_in,
                              void* d_out, int out_size, void* d_ws, size_t ws_size,
                              hipStream_t stream) {
    const float* feat = (const float*)d_in[0];
    const int*   ei   = (const int*)d_in[1];
    const float* Wq   = (const float*)d_in[2];
    const float* bq   = (const float*)d_in[3];
    const float* Wk   = (const float*)d_in[4];
    const float* bk   = (const float*)d_in[5];
    const float* qp   = (const float*)d_in[6];

    int D = in_sizes[2] / 4;          // 256
    int N = in_sizes[0] / D;          // 50000
    int E = in_sizes[1] / 2;          // 800000
    (void)D;

    int*   bar     = (int*)d_ws;                 // 128 ints (512 B), 4 used, padded
    float* partial = (float*)d_ws + 128;         // GB floats
    float* qtab    = partial + GB;               // 4N floats (16B-aligned: offset 640*4B)
    float* ktab    = qtab + (size_t)N * 4;       // 4N floats
    float* out     = (float*)d_out;

    hipMemsetAsync(d_ws, 0, 512, stream);        // zero barrier counters/flags
    fused_qattn<<<GB, BT, 0, stream>>>(feat, ei, Wq, bq, Wk, bk, qp,
                                       bar, partial, qtab, ktab, out, N, E);
}

// Round 6
// 34.303 us; speedup vs baseline: 3.1530x; 3.1530x over previous
//
#include <hip/hip_runtime.h>
#include <math.h>

#define HALF_PI   1.57079632679489662f
#define INV_SQRT2 0.70710678118654752f
#define BT    256
#define GBF   2048                 // fused grid: 8 blocks/CU x 256 CU (full machine)
#define NTHF  (GBF * BT)           // 524288 threads; E <= 2*NTHF = 1048576
#define NPART 1024                 // fallback edge-kernel blocks

// ---------------------------------------------------------------------------
// Distributed grid barrier: 64 padded counters (arrival spread, no single-line
// RMW hotspot); wave 0 of each block polls all 64 and shuffle-reduces until
// total == GBF. Release on arrival / acquire on poll (AGENT scope) gives the
// cross-XCD visibility (same __hip_atomic pattern that validated in R5).
// ---------------------------------------------------------------------------
__device__ __forceinline__ void gridbar(int* cnt) {
    __syncthreads();
    const int tid = threadIdx.x;
    if (tid == 0) {
        __hip_atomic_fetch_add(&cnt[(blockIdx.x & 63) * 16], 1,
                               __ATOMIC_RELEASE, __HIP_MEMORY_SCOPE_AGENT);
    }
    if (tid < 64) {
        int total;
        for (;;) {
            int v = __hip_atomic_load(&cnt[tid * 16],
                                      __ATOMIC_ACQUIRE, __HIP_MEMORY_SCOPE_AGENT);
            total = v;
            #pragma unroll
            for (int off = 32; off > 0; off >>= 1) total += __shfl_xor(total, off, 64);
            if (total >= GBF) break;
            __builtin_amdgcn_s_sleep(4);
        }
    }
    __syncthreads();
}

// 4-qubit real circuit for one edge: returns exp(attn/4)
__device__ __forceinline__ float edge_ex(float4 qv, float4 kv,
                                         const float* scz, const float* scx) {
    float qa[4] = {qv.x, qv.y, qv.z, qv.w};
    float ka[4] = {kv.x, kv.y, kv.z, kv.w};
    float u[4][2];
    #pragma unroll
    for (int w = 0; w < 4; ++w) {
        float s, c;
        __sincosf(qa[w] * 0.5f, &s, &c);
        u[w][0] = (c + s) * INV_SQRT2;
        u[w][1] = (c - s) * INV_SQRT2;
    }
    float a[16];
    #pragma unroll
    for (int x = 0; x < 16; ++x)
        a[x] = u[0][(x >> 3) & 1] * u[1][(x >> 2) & 1] *
               u[2][(x >> 1) & 1] * u[3][x & 1];
    #pragma unroll
    for (int w = 0; w < 4; ++w) {
        float si, co;
        __sincosf(ka[w] * 0.5f, &si, &co);
        const int cb = 1 << (3 - w);
        const int tb = 1 << (3 - ((w + 1) & 3));
        #pragma unroll
        for (int x = 0; x < 16; ++x) {
            if ((x & cb) && !(x & tb)) {
                float a0 = a[x], a1 = a[x | tb];
                a[x]      = co * a0 - si * a1;
                a[x | tb] = si * a0 + co * a1;
            }
        }
    }
    float attn = 0.f;
    #pragma unroll
    for (int q = 0; q < 4; ++q) {
        const int bit = 1 << (3 - q);
        float sz = 0.f, sx = 0.f;
        #pragma unroll
        for (int x = 0; x < 16; ++x) {
            float pp = a[x] * a[x];
            sz += (x & bit) ? -pp : pp;
            if (!(x & bit)) sx += a[x] * a[x | bit];
        }
        attn += scz[q] * sz - scx[q] * (2.f * sx);
    }
    return __expf(attn * 0.25f);
}

// ---------------------------------------------------------------------------
// Fused kernel, grid MUST be exactly GBF blocks (guaranteed co-resident via
// __launch_bounds__(BT,8): VGPR<=64 -> 8 blocks/CU -> capacity 2048).
// ---------------------------------------------------------------------------
__global__ __launch_bounds__(BT, 8) void fused_qattn(
        const float* __restrict__ feat, const int* __restrict__ ei,
        const float* __restrict__ Wq, const float* __restrict__ bq,
        const float* __restrict__ Wk, const float* __restrict__ bk,
        const float* __restrict__ qp,
        int* barA, int* barB, float* partial, float* qtab, float* ktab,
        float* __restrict__ out, int N, int E)
{
    __shared__ float scz[4], scx[4];
    __shared__ float red[BT];
    const int tid  = threadIdx.x;
    const int gtid = blockIdx.x * BT + tid;

    if (tid < 4) {
        float phi = qp[3 * tid + 0];
        float th  = qp[3 * tid + 1];
        float sth, cth;
        sincosf(th, &sth, &cth);
        scz[tid] = cth;
        scx[tid] = sth * cosf(phi);
    }

    // ---------------- Phase A: node projections (8192 waves) ----------------
    {
        const int lane = tid & 63;
        const int wid  = gtid >> 6;
        const int nwid = NTHF >> 6;   // 8192

        float4 wq4[4], wk4[4];
        #pragma unroll
        for (int q = 0; q < 4; ++q) {
            wq4[q] = reinterpret_cast<const float4*>(Wq + q * 256)[lane];
            wk4[q] = reinterpret_cast<const float4*>(Wk + q * 256)[lane];
        }
        const int   g    = lane >> 3;
        const float bias = (g < 4) ? bq[g] : bk[g & 3];
        const bool hi  = (lane & 32) != 0;
        const bool s16 = (lane & 16) != 0;
        const bool s8  = (lane & 8)  != 0;

        for (int n = wid; n < N; n += nwid) {
            float4 f = reinterpret_cast<const float4*>(feat)[(size_t)n * 64 + lane];
            float acc[8];
            #pragma unroll
            for (int q = 0; q < 4; ++q) {
                acc[q]     = f.x * wq4[q].x + f.y * wq4[q].y + f.z * wq4[q].z + f.w * wq4[q].w;
                acc[4 + q] = f.x * wk4[q].x + f.y * wk4[q].y + f.z * wk4[q].z + f.w * wk4[q].w;
            }
            // multi-value butterfly: 10 shuffles per node
            #pragma unroll
            for (int j = 0; j < 4; ++j) {
                float give = hi ? acc[j] : acc[j + 4];
                float r = __shfl_xor(give, 32, 64);
                acc[j]     += hi ? 0.f : r;
                acc[j + 4] += hi ? r : 0.f;
            }
            #pragma unroll
            for (int j = 0; j < 2; ++j) {
                float giveLow  = hi ? acc[6 + j] : acc[2 + j];
                float giveHigh = hi ? acc[4 + j] : acc[j];
                float give = s16 ? giveHigh : giveLow;
                float r = __shfl_xor(give, 16, 64);
                acc[j]     += (!hi && !s16) ? r : 0.f;
                acc[2 + j] += (!hi &&  s16) ? r : 0.f;
                acc[4 + j] += ( hi && !s16) ? r : 0.f;
                acc[6 + j] += ( hi &&  s16) ? r : 0.f;
            }
            float a_even = hi ? (s16 ? acc[6] : acc[4]) : (s16 ? acc[2] : acc[0]);
            float a_odd  = hi ? (s16 ? acc[7] : acc[5]) : (s16 ? acc[3] : acc[1]);
            float give3 = s8 ? a_even : a_odd;
            float r3 = __shfl_xor(give3, 8, 64);
            float v = (s8 ? a_odd : a_even) + r3;
            v += __shfl_xor(v, 4, 64);
            v += __shfl_xor(v, 2, 64);
            v += __shfl_xor(v, 1, 64);

            if ((lane & 7) == 0) {
                float t = tanhf(v + bias) * HALF_PI;
                if (g < 4) qtab[(size_t)n * 4 + g] = t;
                else       ktab[(size_t)n * 4 + (g & 3)] = t;
            }
        }
    }

    gridbar(barA);

    // ---------------- Phase B: per-edge circuit (1 edge/thread/round) -------
    const float4* qtab4 = reinterpret_cast<const float4*>(qtab);
    const float4* ktab4 = reinterpret_cast<const float4*>(ktab);

    float ex[2];
    float lsum = 0.f;
    #pragma unroll
    for (int it = 0; it < 2; ++it) {
        const int e = gtid + it * NTHF;
        ex[it] = 0.f;
        if (e < E) {
            const int s = ei[e];
            const int d = ei[E + e];
            float v = edge_ex(qtab4[s], ktab4[d], scz, scx);
            ex[it] = v;
            lsum += v;
        }
    }

    red[tid] = lsum;
    __syncthreads();
    #pragma unroll
    for (int s = 128; s > 0; s >>= 1) {
        if (tid < s) red[tid] += red[tid + s];
        __syncthreads();
    }
    if (tid == 0) partial[blockIdx.x] = red[0];

    gridbar(barB);

    // ---------------- Phase C: redundant deterministic reduce + write -------
    float ps = 0.f;
    #pragma unroll
    for (int k = 0; k < GBF / BT; ++k) ps += partial[tid + k * BT];
    red[tid] = ps;
    __syncthreads();
    #pragma unroll
    for (int s = 128; s > 0; s >>= 1) {
        if (tid < s) red[tid] += red[tid + s];
        __syncthreads();
    }
    const float inv = 1.f / red[0];

    #pragma unroll
    for (int it = 0; it < 2; ++it) {
        const int e = gtid + it * NTHF;
        if (e < E) out[e] = ex[it] * inv;
    }
}

// ======================= Fallback: proven 3-kernel path =====================
__global__ __launch_bounds__(256) void node_qk(
        const float* __restrict__ feat,
        const float* __restrict__ Wq, const float* __restrict__ bq,
        const float* __restrict__ Wk, const float* __restrict__ bk,
        float* __restrict__ qtab, float* __restrict__ ktab, int N) {
    const int lane  = threadIdx.x & 63;
    const int wid   = (int)((blockIdx.x * blockDim.x + threadIdx.x) >> 6);
    const int nwid  = (int)((gridDim.x * blockDim.x) >> 6);
    float4 wq4[4], wk4[4];
    #pragma unroll
    for (int q = 0; q < 4; ++q) {
        wq4[q] = reinterpret_cast<const float4*>(Wq + q * 256)[lane];
        wk4[q] = reinterpret_cast<const float4*>(Wk + q * 256)[lane];
    }
    const int  g    = lane >> 3;
    const float bias = (g < 4) ? bq[g] : bk[g & 3];
    const bool hi  = (lane & 32) != 0;
    const bool s16 = (lane & 16) != 0;
    const bool s8  = (lane & 8)  != 0;
    for (int n = wid; n < N; n += nwid) {
        float4 f = reinterpret_cast<const float4*>(feat)[(size_t)n * 64 + lane];
        float acc[8];
        #pragma unroll
        for (int q = 0; q < 4; ++q) {
            acc[q]     = f.x * wq4[q].x + f.y * wq4[q].y + f.z * wq4[q].z + f.w * wq4[q].w;
            acc[4 + q] = f.x * wk4[q].x + f.y * wk4[q].y + f.z * wk4[q].z + f.w * wk4[q].w;
        }
        #pragma unroll
        for (int j = 0; j < 4; ++j) {
            float give = hi ? acc[j] : acc[j + 4];
            float r = __shfl_xor(give, 32, 64);
            acc[j]     += hi ? 0.f : r;
            acc[j + 4] += hi ? r : 0.f;
        }
        #pragma unroll
        for (int j = 0; j < 2; ++j) {
            float giveLow  = hi ? acc[6 + j] : acc[2 + j];
            float giveHigh = hi ? acc[4 + j] : acc[j];
            float give = s16 ? giveHigh : giveLow;
            float r = __shfl_xor(give, 16, 64);
            acc[j]     += (!hi && !s16) ? r : 0.f;
            acc[2 + j] += (!hi &&  s16) ? r : 0.f;
            acc[4 + j] += ( hi && !s16) ? r : 0.f;
            acc[6 + j] += ( hi &&  s16) ? r : 0.f;
        }
        float a_even = hi ? (s16 ? acc[6] : acc[4]) : (s16 ? acc[2] : acc[0]);
        float a_odd  = hi ? (s16 ? acc[7] : acc[5]) : (s16 ? acc[3] : acc[1]);
        float give3 = s8 ? a_even : a_odd;
        float r3 = __shfl_xor(give3, 8, 64);
        float v = (s8 ? a_odd : a_even) + r3;
        v += __shfl_xor(v, 4, 64);
        v += __shfl_xor(v, 2, 64);
        v += __shfl_xor(v, 1, 64);
        if ((lane & 7) == 0) {
            float t = tanhf(v + bias) * HALF_PI;
            if (g < 4) qtab[(size_t)n * 4 + g] = t;
            else       ktab[(size_t)n * 4 + (g & 3)] = t;
        }
    }
}

__global__ __launch_bounds__(256) void edge_attn(
        const int* __restrict__ ei,
        const float4* __restrict__ qtab, const float4* __restrict__ ktab,
        const float* __restrict__ qp,
        float* __restrict__ out, float* __restrict__ partial, int E) {
    __shared__ float scz[4], scx[4];
    __shared__ float red[256];
    const int tid = threadIdx.x;
    if (tid < 4) {
        float phi = qp[3 * tid + 0];
        float th  = qp[3 * tid + 1];
        float sth, cth;
        sincosf(th, &sth, &cth);
        scz[tid] = cth;
        scx[tid] = sth * cosf(phi);
    }
    __syncthreads();
    const int total = NPART * 256;
    float lsum = 0.f;
    #pragma unroll
    for (int i = 0; i < 4; ++i) {
        const int e = blockIdx.x * 256 + tid + i * total;
        if (e < E) {
            float v = edge_ex(qtab[ei[e]], ktab[ei[E + e]], scz, scx);
            out[e] = v;
            lsum += v;
        }
    }
    red[tid] = lsum;
    __syncthreads();
    #pragma unroll
    for (int s = 128; s > 0; s >>= 1) {
        if (tid < s) red[tid] += red[tid + s];
        __syncthreads();
    }
    if (tid == 0) partial[blockIdx.x] = red[0];
}

__global__ __launch_bounds__(256) void normalize_out(
        float* __restrict__ out, const float* __restrict__ partial, int E) {
    __shared__ float red[256];
    const int tid = threadIdx.x;
    float s = 0.f;
    #pragma unroll
    for (int k = 0; k < NPART / 256; ++k) s += partial[tid + k * 256];
    red[tid] = s;
    __syncthreads();
    #pragma unroll
    for (int st = 128; st > 0; st >>= 1) {
        if (tid < st) red[tid] += red[tid + st];
        __syncthreads();
    }
    const float inv = 1.f / red[0];
    const int total = (int)(gridDim.x * 256);
    for (int e = blockIdx.x * 256 + tid; e < E; e += total)
        out[e] *= inv;
}

extern "C" void kernel_launch(void* const* d_in, const int* in_sizes, int n_in,
                              void* d_out, int out_size, void* d_ws, size_t ws_size,
                              hipStream_t stream) {
    const float* feat = (const float*)d_in[0];
    const int*   ei   = (const int*)d_in[1];
    const float* Wq   = (const float*)d_in[2];
    const float* bq   = (const float*)d_in[3];
    const float* Wk   = (const float*)d_in[4];
    const float* bk   = (const float*)d_in[5];
    const float* qp   = (const float*)d_in[6];

    int D = in_sizes[2] / 4;          // 256
    int N = in_sizes[0] / D;          // 50000
    int E = in_sizes[1] / 2;          // 800000
    (void)D;

    // ws layout
    int*   barA    = (int*)d_ws;                 // 64 counters x 16 ints
    int*   barB    = barA + 1024;                // 64 counters x 16 ints
    float* partial = (float*)d_ws + 2048;        // 2048 floats
    float* qtab    = (float*)d_ws + 4096;        // 4N floats (16B aligned)
    float* ktab    = qtab + (size_t)N * 4;
    float* out     = (float*)d_out;

    // capture-time occupancy check (pure driver query; graph-capture-safe)
    int maxB = 0;
    hipError_t oerr = hipOccupancyMaxActiveBlocksPerMultiprocessor(
        &maxB, reinterpret_cast<const void*>(&fused_qattn), BT, 0);
    const bool fused_ok = (oerr == hipSuccess) && (maxB >= 8) &&
                          (E <= 2 * NTHF);

    if (fused_ok) {
        hipMemsetAsync(d_ws, 0, 8192, stream);   // zero barrier counters
        fused_qattn<<<GBF, BT, 0, stream>>>(feat, ei, Wq, bq, Wk, bk, qp,
                                            barA, barB, partial, qtab, ktab,
                                            out, N, E);
    } else {
        node_qk<<<2048, 256, 0, stream>>>(feat, Wq, bq, Wk, bk, qtab, ktab, N);
        edge_attn<<<NPART, 256, 0, stream>>>(ei, (const float4*)qtab,
                                             (const float4*)ktab, qp, out, partial, E);
        normalize_out<<<1024, 256, 0, stream>>>(out, partial, E);
    }
}